// Round 9
// baseline (539.951 us; speedup 1.0000x reference)
//
#include <hip/hip_runtime.h>
#include <hip/hip_bf16.h>
#include <hip/hip_fp16.h>
#include <math.h>

#define B_SZ   16
#define N_ATOM 286
#define NT     1024            // table entries, r_e = 3*e/(NT-1)
#define HIDW   150
#define FF_DIM 512
#define WPAD   152             // padded row length (38 float4)
#define WROWS  151             // 150 weight rows + 1 bias row

__device__ __forceinline__ float softplus_f(float x) {
  return fmaxf(x, 0.0f) + log1pf(expf(-fabsf(x)));
}
// torch Softplus(beta=5): softplus(5x)/5
__device__ __forceinline__ float sp5_f(float x) {
  float t = 5.0f * x;
  return (fmaxf(t, 0.0f) + log1pf(expf(-fabsf(t)))) * 0.2f;
}

// Pack the four 150x150 hidden matrices (+bias as row 150) into [151][152]
// float4-friendly layout: Wp[m][i][o], m: 0=c0w1 1=c0w2 2=c1w1 3=c1w2.
__global__ __launch_bounds__(256) void prep_kernel(
    const float* __restrict__ w1a, const float* __restrict__ b1a,
    const float* __restrict__ w2a, const float* __restrict__ b2a,
    const float* __restrict__ w1c, const float* __restrict__ b1c,
    const float* __restrict__ w2c, const float* __restrict__ b2c,
    float* __restrict__ Wp) {
  const int m = blockIdx.y;
  const float* W  = (m == 0) ? w1a : (m == 1) ? w2a : (m == 2) ? w1c : w2c;
  const float* Bb = (m == 0) ? b1a : (m == 1) ? b2a : (m == 2) ? b1c : b2c;
  int idx = blockIdx.x * 256 + threadIdx.x;
  if (idx < WROWS * WPAD) {
    int i = idx / WPAD, o = idx % WPAD;
    float v = 0.0f;
    if (o < HIDW) v = (i < HIDW) ? W[i * HIDW + o] : Bb[o];
    Wp[(size_t)m * WROWS * WPAD + idx] = v;
  }
}

// One hidden layer 150->150 for this wave's 2 entries, activations in
// registers: lane jj holds outputs 4jj..4jj+3 (p0 = entry e0, p1 = e0+1).
// h[i] broadcast via __shfl with uniform lane index (v_readlane — no memory).
// Inner loop: 1 coalesced float4 W load + 2 shfl + 8 FMA; fully unrolled,
// VMEM-only dependencies -> deep pipelining.
__device__ __forceinline__ void hlayer_shfl(
    const float* __restrict__ Wp,    // [151][152], row 150 = bias
    float4& p0, float4& p1, int jj) {
  const float4 bb = *(const float4*)(Wp + HIDW * WPAD + 4 * jj);
  float4 a0 = bb, a1 = bb;
  #pragma unroll
  for (int ii = 0; ii < 38; ++ii) {
    #pragma unroll
    for (int c = 0; c < 4; ++c) {
      const int i = 4 * ii + c;
      if (i < HIDW) {
        float4 wv = *(const float4*)(Wp + i * WPAD + 4 * jj);
        float s0 = (c == 0) ? p0.x : (c == 1) ? p0.y : (c == 2) ? p0.z : p0.w;
        float s1 = (c == 0) ? p1.x : (c == 1) ? p1.y : (c == 2) ? p1.z : p1.w;
        float h0 = __shfl(s0, ii, 64);
        float h1 = __shfl(s1, ii, 64);
        a0.x = __builtin_fmaf(h0, wv.x, a0.x); a1.x = __builtin_fmaf(h1, wv.x, a1.x);
        a0.y = __builtin_fmaf(h0, wv.y, a0.y); a1.y = __builtin_fmaf(h1, wv.y, a1.y);
        a0.z = __builtin_fmaf(h0, wv.z, a0.z); a1.z = __builtin_fmaf(h1, wv.z, a1.z);
        a0.w = __builtin_fmaf(h0, wv.w, a0.w); a1.w = __builtin_fmaf(h1, wv.w, a1.w);
      }
    }
  }
  p0 = make_float4(sp5_f(a0.x), sp5_f(a0.y), sp5_f(a0.z), sp5_f(a0.w));
  p1 = make_float4(sp5_f(a1.x), sp5_f(a1.y), sp5_f(a1.z), sp5_f(a1.w));
}

// Tabulate radial MLP R(r) at NT points, both clouds in one launch.
// Grid = 2*NT/8 = 256 blocks. Block = 4 waves, 2 entries per wave.
// Output table in fp16 (32 B per entry row of 16 values).
__global__ __launch_bounds__(256) void table_kernel(
    const float* __restrict__ a_w0, const float* __restrict__ a_b0,
    const float* __restrict__ a_w3, const float* __restrict__ a_b3,
    const float* __restrict__ c_w0, const float* __restrict__ c_b0,
    const float* __restrict__ c_w3, const float* __restrict__ c_b3,
    const float* __restrict__ Wp,
    __half* __restrict__ tabh0, __half* __restrict__ tabh1) {
  __shared__ float actA[HIDW * 8];   // layer-3 handoff, [i*8 + e]

  const int nblk = NT / 8;                         // 128
  const int cloud = (blockIdx.x >= nblk) ? 1 : 0;
  const int blk   = blockIdx.x - cloud * nblk;
  const float* w0 = cloud ? c_w0 : a_w0;  const float* b0 = cloud ? c_b0 : a_b0;
  const float* w3 = cloud ? c_w3 : a_w3;  const float* b3 = cloud ? c_b3 : a_b3;
  const float* Wp1 = Wp + (size_t)(cloud * 2)     * WROWS * WPAD;
  const float* Wp2 = Wp + (size_t)(cloud * 2 + 1) * WROWS * WPAD;
  __half* table = cloud ? tabh1 : tabh0;

  const int tid  = threadIdx.x;
  const int lane = tid & 63;
  const int wave = __builtin_amdgcn_readfirstlane(tid >> 6);
  const int e0   = wave * 2;
  const int gbase = blk * 8;
  const int jj = (lane < 38) ? lane : 37;          // output-column group

  // cosine basis for the wave's two entries
  float x0[3], x1[3];
  #pragma unroll
  for (int k = 0; k < 3; ++k) {
    float r0 = 3.0f * (float)(gbase + e0)     / (float)(NT - 1);
    float r1 = 3.0f * (float)(gbase + e0 + 1) / (float)(NT - 1);
    float d0 = (r0 - 1.5f * (float)k) * (1.0f / 1.5f);
    float d1 = (r1 - 1.5f * (float)k) * (1.0f / 1.5f);
    float c0 = cosf(1.57079632679489662f * d0);
    float c1 = cosf(1.57079632679489662f * d1);
    x0[k] = (fabsf(d0) < 1.0f) ? c0 * c0 : 0.0f;
    x1[k] = (fabsf(d1) < 1.0f) ? c1 * c1 : 0.0f;
  }

  // ---- layer 0: 3 -> 150, results straight into registers p0/p1 ----
  float4 p0, p1;
  {
    float v0[4], v1[4];
    #pragma unroll
    for (int c = 0; c < 4; ++c) {
      int o = 4 * jj + c;
      int oc = (o < HIDW) ? o : (HIDW - 1);
      float w00 = w0[oc], w01 = w0[HIDW + oc], w02 = w0[2 * HIDW + oc];
      float bb = b0[oc];
      v0[c] = sp5_f(bb + x0[0] * w00 + x0[1] * w01 + x0[2] * w02);
      v1[c] = sp5_f(bb + x1[0] * w00 + x1[1] * w01 + x1[2] * w02);
    }
    p0 = make_float4(v0[0], v0[1], v0[2], v0[3]);
    p1 = make_float4(v1[0], v1[1], v1[2], v1[3]);
  }

  // ---- layers 1,2 (register-resident, shfl broadcast) ----
  hlayer_shfl(Wp1, p0, p1, jj);
  hlayer_shfl(Wp2, p0, p1, jj);

  // ---- handoff to LDS for layer 3 ----
  {
    float v0[4] = {p0.x, p0.y, p0.z, p0.w};
    float v1[4] = {p1.x, p1.y, p1.z, p1.w};
    #pragma unroll
    for (int c = 0; c < 4; ++c) {
      int o = 4 * jj + c;
      if (o < HIDW) *(float2*)(actA + o * 8 + e0) = make_float2(v0[c], v1[c]);
    }
  }
  __syncthreads();

  // ---- layer 3: 150 -> 16. lanes = 16 outputs x 4 i-groups ----
  {
    const int o  = lane & 15;
    const int ig = lane >> 4;
    float a0 = 0.f, a1 = 0.f;
    for (int i = ig; i < HIDW; i += 4) {
      float wv = w3[i * 16 + o];
      float h0 = actA[i * 8 + e0];
      float h1 = actA[i * 8 + e0 + 1];
      a0 = __builtin_fmaf(h0, wv, a0);
      a1 = __builtin_fmaf(h1, wv, a1);
    }
    a0 += __shfl_xor(a0, 16, 64); a0 += __shfl_xor(a0, 32, 64);
    a1 += __shfl_xor(a1, 16, 64); a1 += __shfl_xor(a1, 32, 64);
    if (lane < 16) {
      float bb = b3[o];
      table[(size_t)(gbase + e0)     * 16 + o] = __float2half(a0 + bb);
      table[(size_t)(gbase + e0 + 1) * 16 + o] = __float2half(a1 + bb);
    }
  }
}

__device__ __forceinline__ void cvt8(uint4 q, float* out) {
  const __half2* h = (const __half2*)&q;
  #pragma unroll
  for (int k = 0; k < 4; ++k) {
    float2 f = __half22float2(h[k]);
    out[2 * k] = f.x; out[2 * k + 1] = f.y;
  }
}

// Conv: one wave per output row (z,a). fp16 table: lerp pair = 64 contiguous
// bytes (rows idx, idx+1) = 4 uint4 gathers from L2. No LDS, no atomics.
// conv1 fuses the emb[Z] gather (gather=1); conv2 reads feats_in (gather=0).
__global__ __launch_bounds__(256) void conv_kernel(
    const float* __restrict__ xyz, const int* __restrict__ Z,
    const float* __restrict__ emb, const float* __restrict__ feats_in,
    const __half* __restrict__ tabh, float* __restrict__ f_out, int gather) {
  const int wave = threadIdx.x >> 6;
  const int lane = threadIdx.x & 63;
  const int row = blockIdx.x * 4 + wave;
  if (row >= B_SZ * N_ATOM) return;
  const int z = row / N_ATOM, a = row % N_ATOM;
  const float* xz = xyz + (size_t)z * N_ATOM * 3;
  const float ax = xz[a * 3 + 0], ay = xz[a * 3 + 1], az = xz[a * 3 + 2];

  float acc[4] = {0.f, 0.f, 0.f, 0.f};
  float cnt = 0.f;
  for (int b = lane; b < N_ATOM; b += 64) {
    float bx = xz[b * 3 + 0], by = xz[b * 3 + 1], bz = xz[b * 3 + 2];
    float dx = ax - bx, dy = ay - by, dz = az - bz;
    float r = sqrtf(dx * dx + dy * dy + dz * dz + 1e-12f);
    if (r < 3.0f) {
      cnt += 1.0f;
      float t = r * ((float)(NT - 1) / 3.0f);
      int idx = (int)t;
      if (idx > NT - 2) idx = NT - 2;
      float fr = t - (float)idx;
      const uint4* Tp = (const uint4*)(tabh + (size_t)idx * 16);  // 32B-aligned
      uint4 q0 = Tp[0], q1 = Tp[1], q2 = Tp[2], q3 = Tp[3];
      float4 fb;
      if (gather) {
        int zi = Z[z * N_ATOM + b];
        fb = *(const float4*)(emb + (size_t)zi * 4);
      } else {
        fb = *(const float4*)(feats_in + ((size_t)z * N_ATOM + b) * 4);
      }
      float r0[16], r1[16];
      cvt8(q0, r0); cvt8(q1, r0 + 8);
      cvt8(q2, r1); cvt8(q3, r1 + 8);
      #pragma unroll
      for (int i = 0; i < 4; ++i) {
        float v0 = r0[4 * i + 0] + fr * (r1[4 * i + 0] - r0[4 * i + 0]);
        float v1 = r0[4 * i + 1] + fr * (r1[4 * i + 1] - r0[4 * i + 1]);
        float v2 = r0[4 * i + 2] + fr * (r1[4 * i + 2] - r0[4 * i + 2]);
        float v3 = r0[4 * i + 3] + fr * (r1[4 * i + 3] - r0[4 * i + 3]);
        acc[i] += v0 * fb.x + v1 * fb.y + v2 * fb.z + v3 * fb.w;
      }
    }
  }
  #pragma unroll
  for (int m = 32; m > 0; m >>= 1) {
    #pragma unroll
    for (int i = 0; i < 4; ++i) acc[i] += __shfl_xor(acc[i], m, 64);
    cnt += __shfl_xor(cnt, m, 64);
  }
  if (lane == 0) {
    float nb = cnt < 1.0f ? 1.0f : cnt;
    float sc = 1.0f / sqrtf(nb);
    float4 o;
    o.x = acc[0] * sc; o.y = acc[1] * sc; o.z = acc[2] * sc; o.w = acc[3] * sc;
    *(float4*)(f_out + (size_t)row * 4) = o;
  }
}

// Parallel L2-pool: block z reduces sum of squares over atoms for all 8
// channels (4 from f1, 4 from f2). Coalesced float4 loads, shfl reduce.
__global__ __launch_bounds__(256) void pool_kernel(
    const float* __restrict__ f1, const float* __restrict__ f2,
    float* __restrict__ pool_sq) {
  __shared__ float red[4][8];
  const int z = blockIdx.x;
  const int tid = threadIdx.x;
  const int lane = tid & 63, wave = tid >> 6;
  float s[8] = {0.f, 0.f, 0.f, 0.f, 0.f, 0.f, 0.f, 0.f};
  for (int a = tid; a < N_ATOM; a += 256) {
    float4 v1 = *(const float4*)(f1 + ((size_t)z * N_ATOM + a) * 4);
    float4 v2 = *(const float4*)(f2 + ((size_t)z * N_ATOM + a) * 4);
    s[0] += v1.x * v1.x; s[1] += v1.y * v1.y;
    s[2] += v1.z * v1.z; s[3] += v1.w * v1.w;
    s[4] += v2.x * v2.x; s[5] += v2.y * v2.y;
    s[6] += v2.z * v2.z; s[7] += v2.w * v2.w;
  }
  #pragma unroll
  for (int m = 32; m > 0; m >>= 1) {
    #pragma unroll
    for (int k = 0; k < 8; ++k) s[k] += __shfl_xor(s[k], m, 64);
  }
  if (lane == 0) {
    #pragma unroll
    for (int k = 0; k < 8; ++k) red[wave][k] = s[k];
  }
  __syncthreads();
  if (tid < 8)
    pool_sq[z * 8 + tid] = red[0][tid] + red[1][tid] + red[2][tid] + red[3][tid];
}

// FC(8->512)+softplus -> batchnorm over B -> softplus -> FC(512->1) ->
// sigmoid. Pooling pre-reduced into pool_sq by pool_kernel.
__global__ __launch_bounds__(512) void tail_kernel(
    const float* __restrict__ pool_sq,
    const float* __restrict__ fc_w, const float* __restrict__ fc_b,
    const float* __restrict__ bn_g, const float* __restrict__ bn_b,
    const float* __restrict__ out_w, const float* __restrict__ out_b,
    float* __restrict__ out) {
  __shared__ float pooled[16][8];
  __shared__ float part[8][16];
  const int tid = threadIdx.x;

  if (tid < 128) pooled[tid >> 3][tid & 7] = sqrtf(pool_sq[tid]);
  __syncthreads();

  const int f = tid;
  float hv[16];
  float mean = 0.f;
  #pragma unroll
  for (int z = 0; z < 16; ++z) {
    float a = fc_b[f];
    #pragma unroll
    for (int c = 0; c < 8; ++c) a += pooled[z][c] * fc_w[c * FF_DIM + f];
    hv[z] = softplus_f(a);
    mean += hv[z];
  }
  mean *= (1.0f / 16.0f);
  float var = 0.f;
  #pragma unroll
  for (int z = 0; z < 16; ++z) { float d = hv[z] - mean; var += d * d; }
  var *= (1.0f / 16.0f);
  float istd = 1.0f / sqrtf(var + 1e-5f);
  float g = bn_g[f], bb = bn_b[f], ow = out_w[f];
  float contrib[16];
  #pragma unroll
  for (int z = 0; z < 16; ++z)
    contrib[z] = softplus_f((hv[z] - mean) * istd * g + bb) * ow;

  const int lane = tid & 63, wv = tid >> 6;
  #pragma unroll
  for (int m = 32; m > 0; m >>= 1) {
    #pragma unroll
    for (int z = 0; z < 16; ++z) contrib[z] += __shfl_xor(contrib[z], m, 64);
  }
  if (lane == 0) {
    #pragma unroll
    for (int z = 0; z < 16; ++z) part[wv][z] = contrib[z];
  }
  __syncthreads();
  if (tid < 16) {
    float s = out_b[0];
    #pragma unroll
    for (int w8 = 0; w8 < 8; ++w8) s += part[w8][tid];
    out[tid] = 1.0f / (1.0f + expf(-s));
  }
}

extern "C" void kernel_launch(void* const* d_in, const int* in_sizes, int n_in,
                              void* d_out, int out_size, void* d_ws, size_t ws_size,
                              hipStream_t stream) {
  const float* xyz = (const float*)d_in[0];
  const int*   Z   = (const int*)d_in[1];
  const float* emb = (const float*)d_in[2];
  const float* c0[8]; const float* c1[8];
  for (int i = 0; i < 8; ++i) {
    c0[i] = (const float*)d_in[3 + i];
    c1[i] = (const float*)d_in[11 + i];
  }
  const float* fc_w  = (const float*)d_in[19];
  const float* fc_b  = (const float*)d_in[20];
  const float* bn_g  = (const float*)d_in[21];
  const float* bn_b  = (const float*)d_in[22];
  const float* out_w = (const float*)d_in[23];
  const float* out_b = (const float*)d_in[24];
  float* out = (float*)d_out;

  // ws layout (fp32 region first, then fp16 tables)
  float* wsf = (float*)d_ws;
  float* Wp = wsf;                                             // 4*151*152 f32
  float* f1 = Wp + (size_t)4 * WROWS * WPAD;                   // 16*286*4 f32
  float* f2 = f1 + (size_t)B_SZ * N_ATOM * 4;
  float* pool_sq = f2 + (size_t)B_SZ * N_ATOM * 4;             // 128 f32
  __half* tabh0 = (__half*)(pool_sq + 128);                    // NT*16 f16
  __half* tabh1 = tabh0 + (size_t)NT * 16;

  {
    dim3 g((WROWS * WPAD + 255) / 256, 4);
    prep_kernel<<<g, 256, 0, stream>>>(c0[2], c0[3], c0[4], c0[5],
                                       c1[2], c1[3], c1[4], c1[5], Wp);
  }

  table_kernel<<<2 * (NT / 8), 256, 0, stream>>>(
      c0[0], c0[1], c0[6], c0[7],
      c1[0], c1[1], c1[6], c1[7],
      Wp, tabh0, tabh1);

  const int conv_blocks = (B_SZ * N_ATOM + 3) / 4;   // 1144
  conv_kernel<<<conv_blocks, 256, 0, stream>>>(xyz, Z, emb, (const float*)nullptr,
                                               tabh0, f1, 1);
  conv_kernel<<<conv_blocks, 256, 0, stream>>>(xyz, Z, emb, f1,
                                               tabh1, f2, 0);

  pool_kernel<<<B_SZ, 256, 0, stream>>>(f1, f2, pool_sq);

  tail_kernel<<<1, 512, 0, stream>>>(pool_sq, fc_w, fc_b, bn_g, bn_b,
                                     out_w, out_b, out);
}

// Round 10
// 183.560 us; speedup vs baseline: 2.9415x; 2.9415x over previous
//
#include <hip/hip_runtime.h>
#include <hip/hip_bf16.h>
#include <hip/hip_fp16.h>
#include <math.h>

#define B_SZ   16
#define N_ATOM 286
#define NT     1024            // table entries, r_e = 3*e/(NT-1)
#define HIDW   150
#define FF_DIM 512
#define WPAD   152             // padded row length (38 float4)
#define WROWS  151             // 150 weight rows + 1 bias row

__device__ __forceinline__ float softplus_f(float x) {
  return fmaxf(x, 0.0f) + log1pf(expf(-fabsf(x)));
}
// torch Softplus(beta=5): softplus(5x)/5
__device__ __forceinline__ float sp5_f(float x) {
  float t = 5.0f * x;
  return (fmaxf(t, 0.0f) + log1pf(expf(-fabsf(t)))) * 0.2f;
}

// Pack the four 150x150 hidden matrices (+bias as row 150) into [151][152]
// float4-friendly layout: Wp[m][i][o], m: 0=c0w1 1=c0w2 2=c1w1 3=c1w2.
__global__ __launch_bounds__(256) void prep_kernel(
    const float* __restrict__ w1a, const float* __restrict__ b1a,
    const float* __restrict__ w2a, const float* __restrict__ b2a,
    const float* __restrict__ w1c, const float* __restrict__ b1c,
    const float* __restrict__ w2c, const float* __restrict__ b2c,
    float* __restrict__ Wp) {
  const int m = blockIdx.y;
  const float* W  = (m == 0) ? w1a : (m == 1) ? w2a : (m == 2) ? w1c : w2c;
  const float* Bb = (m == 0) ? b1a : (m == 1) ? b2a : (m == 2) ? b1c : b2c;
  int idx = blockIdx.x * 256 + threadIdx.x;
  if (idx < WROWS * WPAD) {
    int i = idx / WPAD, o = idx % WPAD;
    float v = 0.0f;
    if (o < HIDW) v = (i < HIDW) ? W[i * HIDW + o] : Bb[o];
    Wp[(size_t)m * WROWS * WPAD + idx] = v;
  }
}

// One hidden layer 150->150 for this wave's 2 entries (e0, e0+1).
// lane jj (0..37) owns outputs 4jj..4jj+3; one coalesced float4 weight load
// per reduction step, unroll-8 pipelined. Activations via uniform LDS
// broadcast. Act columns are wave-private -> no barriers.
__device__ __forceinline__ void hidden_layer_v2(
    const float* __restrict__ Wp,    // [151][152], row 150 = bias
    const float* __restrict__ src,   // act LDS, layout [i*8 + e]
    float* __restrict__ dst,
    int jj, int e0) {
  const float4 bb = *(const float4*)(Wp + HIDW * WPAD + 4 * jj);
  float4 a0 = bb, a1 = bb;          // a0: entry e0, a1: entry e0+1
  #pragma unroll 8
  for (int i = 0; i < HIDW; ++i) {
    float4 wv = *(const float4*)(Wp + i * WPAD + 4 * jj);
    float2 h  = *(const float2*)(src + i * 8 + e0);   // uniform broadcast
    a0.x = __builtin_fmaf(h.x, wv.x, a0.x); a1.x = __builtin_fmaf(h.y, wv.x, a1.x);
    a0.y = __builtin_fmaf(h.x, wv.y, a0.y); a1.y = __builtin_fmaf(h.y, wv.y, a1.y);
    a0.z = __builtin_fmaf(h.x, wv.z, a0.z); a1.z = __builtin_fmaf(h.y, wv.z, a1.z);
    a0.w = __builtin_fmaf(h.x, wv.w, a0.w); a1.w = __builtin_fmaf(h.y, wv.w, a1.w);
  }
  *(float2*)(dst + (4 * jj + 0) * 8 + e0) = make_float2(sp5_f(a0.x), sp5_f(a1.x));
  *(float2*)(dst + (4 * jj + 1) * 8 + e0) = make_float2(sp5_f(a0.y), sp5_f(a1.y));
  *(float2*)(dst + (4 * jj + 2) * 8 + e0) = make_float2(sp5_f(a0.z), sp5_f(a1.z));
  *(float2*)(dst + (4 * jj + 3) * 8 + e0) = make_float2(sp5_f(a0.w), sp5_f(a1.w));
}

// Tabulate radial MLP R(r) at NT points, both clouds in one launch.
// Grid = 2*NT/8 = 256 blocks. Block = 4 waves, 2 entries per wave.
// Output table in fp16 (32 B per entry row of 16 values).
__global__ __launch_bounds__(256) void table_kernel(
    const float* __restrict__ a_w0, const float* __restrict__ a_b0,
    const float* __restrict__ a_w3, const float* __restrict__ a_b3,
    const float* __restrict__ c_w0, const float* __restrict__ c_b0,
    const float* __restrict__ c_w3, const float* __restrict__ c_b3,
    const float* __restrict__ Wp,
    __half* __restrict__ tabh0, __half* __restrict__ tabh1) {
  __shared__ float actA[WPAD * 8];   // 4.9 KB, [o*8 + e], e = wave*2 + {0,1}
  __shared__ float actB[WPAD * 8];

  const int nblk = NT / 8;                         // 128
  const int cloud = (blockIdx.x >= nblk) ? 1 : 0;
  const int blk   = blockIdx.x - cloud * nblk;
  const float* w0 = cloud ? c_w0 : a_w0;  const float* b0 = cloud ? c_b0 : a_b0;
  const float* w3 = cloud ? c_w3 : a_w3;  const float* b3 = cloud ? c_b3 : a_b3;
  const float* Wp1 = Wp + (size_t)(cloud * 2)     * WROWS * WPAD;
  const float* Wp2 = Wp + (size_t)(cloud * 2 + 1) * WROWS * WPAD;
  __half* table = cloud ? tabh1 : tabh0;

  const int tid  = threadIdx.x;
  const int lane = tid & 63;
  const int wave = __builtin_amdgcn_readfirstlane(tid >> 6);
  const int e0   = wave * 2;
  const int gbase = blk * 8;
  const int jj = (lane < 38) ? lane : 37;          // weight-column group

  // cosine basis for the wave's two entries
  float x0[3], x1[3];
  #pragma unroll
  for (int k = 0; k < 3; ++k) {
    float r0 = 3.0f * (float)(gbase + e0)     / (float)(NT - 1);
    float r1 = 3.0f * (float)(gbase + e0 + 1) / (float)(NT - 1);
    float d0 = (r0 - 1.5f * (float)k) * (1.0f / 1.5f);
    float d1 = (r1 - 1.5f * (float)k) * (1.0f / 1.5f);
    float c0 = cosf(1.57079632679489662f * d0);
    float c1 = cosf(1.57079632679489662f * d1);
    x0[k] = (fabsf(d0) < 1.0f) ? c0 * c0 : 0.0f;
    x1[k] = (fabsf(d1) < 1.0f) ? c1 * c1 : 0.0f;
  }

  // ---- layer 0: 3 -> 150 ----
  #pragma unroll
  for (int c = 0; c < 3; ++c) {
    int o = lane + 64 * c;
    int oc = (o < HIDW) ? o : (HIDW - 1);
    float w00 = w0[oc], w01 = w0[HIDW + oc], w02 = w0[2 * HIDW + oc], bb = b0[oc];
    float h0 = sp5_f(bb + x0[0] * w00 + x0[1] * w01 + x0[2] * w02);
    float h1 = sp5_f(bb + x1[0] * w00 + x1[1] * w01 + x1[2] * w02);
    if (o < HIDW) *(float2*)(actA + o * 8 + e0) = make_float2(h0, h1);
  }
  // wave-private columns: no barrier needed

  // ---- layers 1,2 ----
  hidden_layer_v2(Wp1, actA, actB, jj, e0);
  hidden_layer_v2(Wp2, actB, actA, jj, e0);

  // ---- layer 3: 150 -> 16. lanes = 16 outputs x 4 i-groups ----
  {
    const int o  = lane & 15;
    const int ig = lane >> 4;
    float a0 = 0.f, a1 = 0.f;
    for (int i = ig; i < HIDW; i += 4) {
      float wv = w3[i * 16 + o];
      float h0 = actA[i * 8 + e0];
      float h1 = actA[i * 8 + e0 + 1];
      a0 = __builtin_fmaf(h0, wv, a0);
      a1 = __builtin_fmaf(h1, wv, a1);
    }
    a0 += __shfl_xor(a0, 16, 64); a0 += __shfl_xor(a0, 32, 64);
    a1 += __shfl_xor(a1, 16, 64); a1 += __shfl_xor(a1, 32, 64);
    if (lane < 16) {
      float bb = b3[o];
      table[(size_t)(gbase + e0)     * 16 + o] = __float2half(a0 + bb);
      table[(size_t)(gbase + e0 + 1) * 16 + o] = __float2half(a1 + bb);
    }
  }
}

__device__ __forceinline__ void cvt8(uint4 q, float* out) {
  const __half2* h = (const __half2*)&q;
  #pragma unroll
  for (int k = 0; k < 4; ++k) {
    float2 f = __half22float2(h[k]);
    out[2 * k] = f.x; out[2 * k + 1] = f.y;
  }
}

// Conv: one wave per output row (z,a). fp16 table: lerp pair = 64 contiguous
// bytes (rows idx, idx+1) = 4 uint4 gathers from L2. No LDS, no atomics.
// conv1 fuses the emb[Z] gather (gather=1); conv2 reads feats_in (gather=0).
__global__ __launch_bounds__(256) void conv_kernel(
    const float* __restrict__ xyz, const int* __restrict__ Z,
    const float* __restrict__ emb, const float* __restrict__ feats_in,
    const __half* __restrict__ tabh, float* __restrict__ f_out, int gather) {
  const int wave = threadIdx.x >> 6;
  const int lane = threadIdx.x & 63;
  const int row = blockIdx.x * 4 + wave;
  if (row >= B_SZ * N_ATOM) return;
  const int z = row / N_ATOM, a = row % N_ATOM;
  const float* xz = xyz + (size_t)z * N_ATOM * 3;
  const float ax = xz[a * 3 + 0], ay = xz[a * 3 + 1], az = xz[a * 3 + 2];

  float acc[4] = {0.f, 0.f, 0.f, 0.f};
  float cnt = 0.f;
  for (int b = lane; b < N_ATOM; b += 64) {
    float bx = xz[b * 3 + 0], by = xz[b * 3 + 1], bz = xz[b * 3 + 2];
    float dx = ax - bx, dy = ay - by, dz = az - bz;
    float r = sqrtf(dx * dx + dy * dy + dz * dz + 1e-12f);
    if (r < 3.0f) {
      cnt += 1.0f;
      float t = r * ((float)(NT - 1) / 3.0f);
      int idx = (int)t;
      if (idx > NT - 2) idx = NT - 2;
      float fr = t - (float)idx;
      const uint4* Tp = (const uint4*)(tabh + (size_t)idx * 16);  // 32B-aligned
      uint4 q0 = Tp[0], q1 = Tp[1], q2 = Tp[2], q3 = Tp[3];
      float4 fb;
      if (gather) {
        int zi = Z[z * N_ATOM + b];
        fb = *(const float4*)(emb + (size_t)zi * 4);
      } else {
        fb = *(const float4*)(feats_in + ((size_t)z * N_ATOM + b) * 4);
      }
      float r0[16], r1[16];
      cvt8(q0, r0); cvt8(q1, r0 + 8);
      cvt8(q2, r1); cvt8(q3, r1 + 8);
      #pragma unroll
      for (int i = 0; i < 4; ++i) {
        float v0 = r0[4 * i + 0] + fr * (r1[4 * i + 0] - r0[4 * i + 0]);
        float v1 = r0[4 * i + 1] + fr * (r1[4 * i + 1] - r0[4 * i + 1]);
        float v2 = r0[4 * i + 2] + fr * (r1[4 * i + 2] - r0[4 * i + 2]);
        float v3 = r0[4 * i + 3] + fr * (r1[4 * i + 3] - r0[4 * i + 3]);
        acc[i] += v0 * fb.x + v1 * fb.y + v2 * fb.z + v3 * fb.w;
      }
    }
  }
  #pragma unroll
  for (int m = 32; m > 0; m >>= 1) {
    #pragma unroll
    for (int i = 0; i < 4; ++i) acc[i] += __shfl_xor(acc[i], m, 64);
    cnt += __shfl_xor(cnt, m, 64);
  }
  if (lane == 0) {
    float nb = cnt < 1.0f ? 1.0f : cnt;
    float sc = 1.0f / sqrtf(nb);
    float4 o;
    o.x = acc[0] * sc; o.y = acc[1] * sc; o.z = acc[2] * sc; o.w = acc[3] * sc;
    *(float4*)(f_out + (size_t)row * 4) = o;
  }
}

// Parallel L2-pool: block z reduces sum of squares over atoms for all 8
// channels (4 from f1, 4 from f2). Coalesced float4 loads, shfl reduce.
__global__ __launch_bounds__(256) void pool_kernel(
    const float* __restrict__ f1, const float* __restrict__ f2,
    float* __restrict__ pool_sq) {
  __shared__ float red[4][8];
  const int z = blockIdx.x;
  const int tid = threadIdx.x;
  const int lane = tid & 63, wave = tid >> 6;
  float s[8] = {0.f, 0.f, 0.f, 0.f, 0.f, 0.f, 0.f, 0.f};
  for (int a = tid; a < N_ATOM; a += 256) {
    float4 v1 = *(const float4*)(f1 + ((size_t)z * N_ATOM + a) * 4);
    float4 v2 = *(const float4*)(f2 + ((size_t)z * N_ATOM + a) * 4);
    s[0] += v1.x * v1.x; s[1] += v1.y * v1.y;
    s[2] += v1.z * v1.z; s[3] += v1.w * v1.w;
    s[4] += v2.x * v2.x; s[5] += v2.y * v2.y;
    s[6] += v2.z * v2.z; s[7] += v2.w * v2.w;
  }
  #pragma unroll
  for (int m = 32; m > 0; m >>= 1) {
    #pragma unroll
    for (int k = 0; k < 8; ++k) s[k] += __shfl_xor(s[k], m, 64);
  }
  if (lane == 0) {
    #pragma unroll
    for (int k = 0; k < 8; ++k) red[wave][k] = s[k];
  }
  __syncthreads();
  if (tid < 8)
    pool_sq[z * 8 + tid] = red[0][tid] + red[1][tid] + red[2][tid] + red[3][tid];
}

// FC(8->512)+softplus -> batchnorm over B -> softplus -> FC(512->1) ->
// sigmoid. Pooling pre-reduced into pool_sq by pool_kernel.
__global__ __launch_bounds__(512) void tail_kernel(
    const float* __restrict__ pool_sq,
    const float* __restrict__ fc_w, const float* __restrict__ fc_b,
    const float* __restrict__ bn_g, const float* __restrict__ bn_b,
    const float* __restrict__ out_w, const float* __restrict__ out_b,
    float* __restrict__ out) {
  __shared__ float pooled[16][8];
  __shared__ float part[8][16];
  const int tid = threadIdx.x;

  if (tid < 128) pooled[tid >> 3][tid & 7] = sqrtf(pool_sq[tid]);
  __syncthreads();

  const int f = tid;
  float hv[16];
  float mean = 0.f;
  #pragma unroll
  for (int z = 0; z < 16; ++z) {
    float a = fc_b[f];
    #pragma unroll
    for (int c = 0; c < 8; ++c) a += pooled[z][c] * fc_w[c * FF_DIM + f];
    hv[z] = softplus_f(a);
    mean += hv[z];
  }
  mean *= (1.0f / 16.0f);
  float var = 0.f;
  #pragma unroll
  for (int z = 0; z < 16; ++z) { float d = hv[z] - mean; var += d * d; }
  var *= (1.0f / 16.0f);
  float istd = 1.0f / sqrtf(var + 1e-5f);
  float g = bn_g[f], bb = bn_b[f], ow = out_w[f];
  float contrib[16];
  #pragma unroll
  for (int z = 0; z < 16; ++z)
    contrib[z] = softplus_f((hv[z] - mean) * istd * g + bb) * ow;

  const int lane = tid & 63, wv = tid >> 6;
  #pragma unroll
  for (int m = 32; m > 0; m >>= 1) {
    #pragma unroll
    for (int z = 0; z < 16; ++z) contrib[z] += __shfl_xor(contrib[z], m, 64);
  }
  if (lane == 0) {
    #pragma unroll
    for (int z = 0; z < 16; ++z) part[wv][z] = contrib[z];
  }
  __syncthreads();
  if (tid < 16) {
    float s = out_b[0];
    #pragma unroll
    for (int w8 = 0; w8 < 8; ++w8) s += part[w8][tid];
    out[tid] = 1.0f / (1.0f + expf(-s));
  }
}

extern "C" void kernel_launch(void* const* d_in, const int* in_sizes, int n_in,
                              void* d_out, int out_size, void* d_ws, size_t ws_size,
                              hipStream_t stream) {
  const float* xyz = (const float*)d_in[0];
  const int*   Z   = (const int*)d_in[1];
  const float* emb = (const float*)d_in[2];
  const float* c0[8]; const float* c1[8];
  for (int i = 0; i < 8; ++i) {
    c0[i] = (const float*)d_in[3 + i];
    c1[i] = (const float*)d_in[11 + i];
  }
  const float* fc_w  = (const float*)d_in[19];
  const float* fc_b  = (const float*)d_in[20];
  const float* bn_g  = (const float*)d_in[21];
  const float* bn_b  = (const float*)d_in[22];
  const float* out_w = (const float*)d_in[23];
  const float* out_b = (const float*)d_in[24];
  float* out = (float*)d_out;

  // ws layout (fp32 region first, then fp16 tables)
  float* wsf = (float*)d_ws;
  float* Wp = wsf;                                             // 4*151*152 f32
  float* f1 = Wp + (size_t)4 * WROWS * WPAD;                   // 16*286*4 f32
  float* f2 = f1 + (size_t)B_SZ * N_ATOM * 4;
  float* pool_sq = f2 + (size_t)B_SZ * N_ATOM * 4;             // 128 f32
  __half* tabh0 = (__half*)(pool_sq + 128);                    // NT*16 f16
  __half* tabh1 = tabh0 + (size_t)NT * 16;

  {
    dim3 g((WROWS * WPAD + 255) / 256, 4);
    prep_kernel<<<g, 256, 0, stream>>>(c0[2], c0[3], c0[4], c0[5],
                                       c1[2], c1[3], c1[4], c1[5], Wp);
  }

  table_kernel<<<2 * (NT / 8), 256, 0, stream>>>(
      c0[0], c0[1], c0[6], c0[7],
      c1[0], c1[1], c1[6], c1[7],
      Wp, tabh0, tabh1);

  const int conv_blocks = (B_SZ * N_ATOM + 3) / 4;   // 1144
  conv_kernel<<<conv_blocks, 256, 0, stream>>>(xyz, Z, emb, (const float*)nullptr,
                                               tabh0, f1, 1);
  conv_kernel<<<conv_blocks, 256, 0, stream>>>(xyz, Z, emb, f1,
                                               tabh1, f2, 0);

  pool_kernel<<<B_SZ, 256, 0, stream>>>(f1, f2, pool_sq);

  tail_kernel<<<1, 512, 0, stream>>>(pool_sq, fc_w, fc_b, bn_g, bn_b,
                                     out_w, out_b, out);
}

// Round 12
// 180.102 us; speedup vs baseline: 2.9980x; 1.0192x over previous
//
#include <hip/hip_runtime.h>
#include <hip/hip_bf16.h>
#include <hip/hip_fp16.h>
#include <math.h>

#define B_SZ   16
#define N_ATOM 286
#define NT     1024            // table entries, r_e = 3*e/(NT-1)
#define HIDW   150
#define FF_DIM 512
#define WPAD   152             // padded row length (38 float4)
#define WROWS  151             // 150 weight rows + 1 bias row
#define BLK_PER_Z 72           // conv blocks per batch element (72*4=288 rows)

__device__ __forceinline__ float softplus_f(float x) {
  return fmaxf(x, 0.0f) + log1pf(expf(-fabsf(x)));
}
// torch Softplus(beta=5): softplus(5x)/5
__device__ __forceinline__ float sp5_f(float x) {
  float t = 5.0f * x;
  return (fmaxf(t, 0.0f) + log1pf(expf(-fabsf(t)))) * 0.2f;
}

// Pack the four 150x150 hidden matrices (+bias as row 150) into [151][152]
// float4-friendly layout: Wp[m][i][o], m: 0=c0w1 1=c0w2 2=c1w1 3=c1w2.
__global__ __launch_bounds__(256) void prep_kernel(
    const float* __restrict__ w1a, const float* __restrict__ b1a,
    const float* __restrict__ w2a, const float* __restrict__ b2a,
    const float* __restrict__ w1c, const float* __restrict__ b1c,
    const float* __restrict__ w2c, const float* __restrict__ b2c,
    float* __restrict__ Wp) {
  const int m = blockIdx.y;
  const float* W  = (m == 0) ? w1a : (m == 1) ? w2a : (m == 2) ? w1c : w2c;
  const float* Bb = (m == 0) ? b1a : (m == 1) ? b2a : (m == 2) ? b1c : b2c;
  int idx = blockIdx.x * 256 + threadIdx.x;
  if (idx < WROWS * WPAD) {
    int i = idx / WPAD, o = idx % WPAD;
    float v = 0.0f;
    if (o < HIDW) v = (i < HIDW) ? W[i * HIDW + o] : Bb[o];
    Wp[(size_t)m * WROWS * WPAD + idx] = v;
  }
}

// Tabulate radial MLP R(r) at NT points, both clouds in one launch.
// Grid = 2*NT/8 = 256 blocks. Block = 4 waves, 2 entries per wave.
// Hidden layers are written INLINE with direct __shared__ access so the
// h-broadcast compiles to ds_read_b64 (lgkmcnt) and the float4 weight loads
// (vmcnt) can stay 10 deep in flight — no flat-load cross-serialization.
__global__ __launch_bounds__(256) void table_kernel(
    const float* __restrict__ a_w0, const float* __restrict__ a_b0,
    const float* __restrict__ a_w3, const float* __restrict__ a_b3,
    const float* __restrict__ c_w0, const float* __restrict__ c_b0,
    const float* __restrict__ c_w3, const float* __restrict__ c_b3,
    const float* __restrict__ Wp,
    __half* __restrict__ tabh0, __half* __restrict__ tabh1) {
  __shared__ float actA[WPAD * 8];   // [o*8 + e], e = wave*2 + {0,1}
  __shared__ float actB[WPAD * 8];

  const int nblk = NT / 8;                         // 128
  const int cloud = (blockIdx.x >= nblk) ? 1 : 0;
  const int blk   = blockIdx.x - cloud * nblk;
  const float* w0 = cloud ? c_w0 : a_w0;  const float* b0 = cloud ? c_b0 : a_b0;
  const float* w3 = cloud ? c_w3 : a_w3;  const float* b3 = cloud ? c_b3 : a_b3;
  const float* __restrict__ Wp1 = Wp + (size_t)(cloud * 2)     * WROWS * WPAD;
  const float* __restrict__ Wp2 = Wp + (size_t)(cloud * 2 + 1) * WROWS * WPAD;
  __half* table = cloud ? tabh1 : tabh0;

  const int tid  = threadIdx.x;
  const int lane = tid & 63;
  const int wave = __builtin_amdgcn_readfirstlane(tid >> 6);
  const int e0   = wave * 2;
  const int gbase = blk * 8;
  const int jj = (lane < 38) ? lane : 37;          // weight-column group

  // cosine basis for the wave's two entries
  float x0[3], x1[3];
  #pragma unroll
  for (int k = 0; k < 3; ++k) {
    float r0 = 3.0f * (float)(gbase + e0)     / (float)(NT - 1);
    float r1 = 3.0f * (float)(gbase + e0 + 1) / (float)(NT - 1);
    float d0 = (r0 - 1.5f * (float)k) * (1.0f / 1.5f);
    float d1 = (r1 - 1.5f * (float)k) * (1.0f / 1.5f);
    float c0 = cosf(1.57079632679489662f * d0);
    float c1 = cosf(1.57079632679489662f * d1);
    x0[k] = (fabsf(d0) < 1.0f) ? c0 * c0 : 0.0f;
    x1[k] = (fabsf(d1) < 1.0f) ? c1 * c1 : 0.0f;
  }

  // ---- layer 0: 3 -> 150 ----
  #pragma unroll
  for (int c = 0; c < 3; ++c) {
    int o = lane + 64 * c;
    int oc = (o < HIDW) ? o : (HIDW - 1);
    float w00 = w0[oc], w01 = w0[HIDW + oc], w02 = w0[2 * HIDW + oc], bb = b0[oc];
    float h0 = sp5_f(bb + x0[0] * w00 + x0[1] * w01 + x0[2] * w02);
    float h1 = sp5_f(bb + x1[0] * w00 + x1[1] * w01 + x1[2] * w02);
    if (o < HIDW) *(float2*)(&actA[o * 8 + e0]) = make_float2(h0, h1);
  }
  // act columns are wave-private -> no barrier

  // ---- layer 1: actA x Wp1 -> actB (inline, direct LDS) ----
  {
    const float* __restrict__ Wb = Wp1 + 4 * jj;
    float4 a0 = *(const float4*)(Wp1 + HIDW * WPAD + 4 * jj);   // bias row
    float4 a1 = a0;
    #pragma unroll 10
    for (int i = 0; i < HIDW; ++i) {
      float4 wv = *(const float4*)(Wb + i * WPAD);
      float2 h  = *(const float2*)(&actA[i * 8 + e0]);   // ds_read_b64 broadcast
      a0.x = __builtin_fmaf(h.x, wv.x, a0.x); a1.x = __builtin_fmaf(h.y, wv.x, a1.x);
      a0.y = __builtin_fmaf(h.x, wv.y, a0.y); a1.y = __builtin_fmaf(h.y, wv.y, a1.y);
      a0.z = __builtin_fmaf(h.x, wv.z, a0.z); a1.z = __builtin_fmaf(h.y, wv.z, a1.z);
      a0.w = __builtin_fmaf(h.x, wv.w, a0.w); a1.w = __builtin_fmaf(h.y, wv.w, a1.w);
    }
    *(float2*)(&actB[(4 * jj + 0) * 8 + e0]) = make_float2(sp5_f(a0.x), sp5_f(a1.x));
    *(float2*)(&actB[(4 * jj + 1) * 8 + e0]) = make_float2(sp5_f(a0.y), sp5_f(a1.y));
    *(float2*)(&actB[(4 * jj + 2) * 8 + e0]) = make_float2(sp5_f(a0.z), sp5_f(a1.z));
    *(float2*)(&actB[(4 * jj + 3) * 8 + e0]) = make_float2(sp5_f(a0.w), sp5_f(a1.w));
  }

  // ---- layer 2: actB x Wp2 -> actA ----
  {
    const float* __restrict__ Wb = Wp2 + 4 * jj;
    float4 a0 = *(const float4*)(Wp2 + HIDW * WPAD + 4 * jj);
    float4 a1 = a0;
    #pragma unroll 10
    for (int i = 0; i < HIDW; ++i) {
      float4 wv = *(const float4*)(Wb + i * WPAD);
      float2 h  = *(const float2*)(&actB[i * 8 + e0]);
      a0.x = __builtin_fmaf(h.x, wv.x, a0.x); a1.x = __builtin_fmaf(h.y, wv.x, a1.x);
      a0.y = __builtin_fmaf(h.x, wv.y, a0.y); a1.y = __builtin_fmaf(h.y, wv.y, a1.y);
      a0.z = __builtin_fmaf(h.x, wv.z, a0.z); a1.z = __builtin_fmaf(h.y, wv.z, a1.z);
      a0.w = __builtin_fmaf(h.x, wv.w, a0.w); a1.w = __builtin_fmaf(h.y, wv.w, a1.w);
    }
    *(float2*)(&actA[(4 * jj + 0) * 8 + e0]) = make_float2(sp5_f(a0.x), sp5_f(a1.x));
    *(float2*)(&actA[(4 * jj + 1) * 8 + e0]) = make_float2(sp5_f(a0.y), sp5_f(a1.y));
    *(float2*)(&actA[(4 * jj + 2) * 8 + e0]) = make_float2(sp5_f(a0.z), sp5_f(a1.z));
    *(float2*)(&actA[(4 * jj + 3) * 8 + e0]) = make_float2(sp5_f(a0.w), sp5_f(a1.w));
  }

  // ---- layer 3: 150 -> 16. lanes = 16 outputs x 4 i-groups ----
  {
    const int o  = lane & 15;
    const int ig = lane >> 4;
    float a0 = 0.f, a1 = 0.f;
    for (int i = ig; i < HIDW; i += 4) {
      float wv = w3[i * 16 + o];
      float h0 = actA[i * 8 + e0];
      float h1 = actA[i * 8 + e0 + 1];
      a0 = __builtin_fmaf(h0, wv, a0);
      a1 = __builtin_fmaf(h1, wv, a1);
    }
    a0 += __shfl_xor(a0, 16, 64); a0 += __shfl_xor(a0, 32, 64);
    a1 += __shfl_xor(a1, 16, 64); a1 += __shfl_xor(a1, 32, 64);
    if (lane < 16) {
      float bb = b3[o];
      table[(size_t)(gbase + e0)     * 16 + o] = __float2half(a0 + bb);
      table[(size_t)(gbase + e0 + 1) * 16 + o] = __float2half(a1 + bb);
    }
  }
}

__device__ __forceinline__ void cvt8(uint4 q, float* out) {
  const __half2* h = (const __half2*)&q;
  #pragma unroll
  for (int k = 0; k < 4; ++k) {
    float2 f = __half22float2(h[k]);
    out[2 * k] = f.x; out[2 * k + 1] = f.y;
  }
}

// Conv: grid = 16 z * 72 blocks, 4 rows per block (one per wave), all same z.
// Coordinates + input features staged in LDS (SoA, conflict-free) once per
// block. Neighbor loop is BRANCHLESS (multiply-mask) so the 4 table gathers
// are unconditional and pipeline. fp16 table lerp pair = 64 contiguous B.
__global__ __launch_bounds__(256) void conv_kernel(
    const float* __restrict__ xyz, const int* __restrict__ Z,
    const float* __restrict__ emb, const float* __restrict__ feats_in,
    const __half* __restrict__ tabh, float* __restrict__ f_out, int gather) {
  __shared__ float xs[N_ATOM], ys[N_ATOM], zs[N_ATOM];
  __shared__ float fxs[N_ATOM], fys[N_ATOM], fzs[N_ATOM], fws[N_ATOM];
  const int tid  = threadIdx.x;
  const int wave = tid >> 6;
  const int lane = tid & 63;
  const int z = blockIdx.x / BLK_PER_Z;
  const int a = (blockIdx.x % BLK_PER_Z) * 4 + wave;

  // ---- stage coords + feats for this z ----
  for (int b = tid; b < N_ATOM; b += 256) {
    const float* p = xyz + ((size_t)z * N_ATOM + b) * 3;
    xs[b] = p[0]; ys[b] = p[1]; zs[b] = p[2];
    float4 fb;
    if (gather) {
      int zi = Z[z * N_ATOM + b];
      fb = *(const float4*)(emb + (size_t)zi * 4);
    } else {
      fb = *(const float4*)(feats_in + ((size_t)z * N_ATOM + b) * 4);
    }
    fxs[b] = fb.x; fys[b] = fb.y; fzs[b] = fb.z; fws[b] = fb.w;
  }
  __syncthreads();
  if (a >= N_ATOM) return;

  const float ax = xs[a], ay = ys[a], az = zs[a];

  float acc[4] = {0.f, 0.f, 0.f, 0.f};
  float cnt = 0.f;
  for (int b = lane; b < N_ATOM; b += 64) {
    float dx = ax - xs[b], dy = ay - ys[b], dz = az - zs[b];
    float r = sqrtf(dx * dx + dy * dy + dz * dz + 1e-12f);
    float msk = (r < 3.0f) ? 1.0f : 0.0f;
    float t = r * ((float)(NT - 1) / 3.0f);
    int idx = (int)t;
    if (idx > NT - 2) idx = NT - 2;
    float fr = t - (float)idx;
    const uint4* Tp = (const uint4*)(tabh + (size_t)idx * 16);  // unconditional
    uint4 q0 = Tp[0], q1 = Tp[1], q2 = Tp[2], q3 = Tp[3];
    float fbx = fxs[b], fby = fys[b], fbz = fzs[b], fbw = fws[b];
    cnt += msk;
    float r0[16], r1[16];
    cvt8(q0, r0); cvt8(q1, r0 + 8);
    cvt8(q2, r1); cvt8(q3, r1 + 8);
    #pragma unroll
    for (int i = 0; i < 4; ++i) {
      float v0 = r0[4 * i + 0] + fr * (r1[4 * i + 0] - r0[4 * i + 0]);
      float v1 = r0[4 * i + 1] + fr * (r1[4 * i + 1] - r0[4 * i + 1]);
      float v2 = r0[4 * i + 2] + fr * (r1[4 * i + 2] - r0[4 * i + 2]);
      float v3 = r0[4 * i + 3] + fr * (r1[4 * i + 3] - r0[4 * i + 3]);
      acc[i] = __builtin_fmaf(msk, v0 * fbx + v1 * fby + v2 * fbz + v3 * fbw,
                              acc[i]);
    }
  }
  #pragma unroll
  for (int m = 32; m > 0; m >>= 1) {
    #pragma unroll
    for (int i = 0; i < 4; ++i) acc[i] += __shfl_xor(acc[i], m, 64);
    cnt += __shfl_xor(cnt, m, 64);
  }
  if (lane == 0) {
    float nb = cnt < 1.0f ? 1.0f : cnt;
    float sc = 1.0f / sqrtf(nb);
    float4 o;
    o.x = acc[0] * sc; o.y = acc[1] * sc; o.z = acc[2] * sc; o.w = acc[3] * sc;
    *(float4*)(f_out + ((size_t)z * N_ATOM + a) * 4) = o;
  }
}

// Parallel L2-pool: block z reduces sum of squares over atoms for all 8
// channels (4 from f1, 4 from f2). Coalesced float4 loads, shfl reduce.
__global__ __launch_bounds__(256) void pool_kernel(
    const float* __restrict__ f1, const float* __restrict__ f2,
    float* __restrict__ pool_sq) {
  __shared__ float red[4][8];
  const int z = blockIdx.x;
  const int tid = threadIdx.x;
  const int lane = tid & 63, wave = tid >> 6;
  float s[8] = {0.f, 0.f, 0.f, 0.f, 0.f, 0.f, 0.f, 0.f};
  for (int a = tid; a < N_ATOM; a += 256) {
    float4 v1 = *(const float4*)(f1 + ((size_t)z * N_ATOM + a) * 4);
    float4 v2 = *(const float4*)(f2 + ((size_t)z * N_ATOM + a) * 4);
    s[0] += v1.x * v1.x; s[1] += v1.y * v1.y;
    s[2] += v1.z * v1.z; s[3] += v1.w * v1.w;
    s[4] += v2.x * v2.x; s[5] += v2.y * v2.y;
    s[6] += v2.z * v2.z; s[7] += v2.w * v2.w;
  }
  #pragma unroll
  for (int m = 32; m > 0; m >>= 1) {
    #pragma unroll
    for (int k = 0; k < 8; ++k) s[k] += __shfl_xor(s[k], m, 64);
  }
  if (lane == 0) {
    #pragma unroll
    for (int k = 0; k < 8; ++k) red[wave][k] = s[k];
  }
  __syncthreads();
  if (tid < 8)
    pool_sq[z * 8 + tid] = red[0][tid] + red[1][tid] + red[2][tid] + red[3][tid];
}

// FC(8->512)+softplus -> batchnorm over B -> softplus -> FC(512->1) ->
// sigmoid. Pooling pre-reduced into pool_sq by pool_kernel.
__global__ __launch_bounds__(512) void tail_kernel(
    const float* __restrict__ pool_sq,
    const float* __restrict__ fc_w, const float* __restrict__ fc_b,
    const float* __restrict__ bn_g, const float* __restrict__ bn_b,
    const float* __restrict__ out_w, const float* __restrict__ out_b,
    float* __restrict__ out) {
  __shared__ float pooled[16][8];
  __shared__ float part[8][16];
  const int tid = threadIdx.x;

  if (tid < 128) pooled[tid >> 3][tid & 7] = sqrtf(pool_sq[tid]);
  __syncthreads();

  const int f = tid;
  float hv[16];
  float mean = 0.f;
  #pragma unroll
  for (int z = 0; z < 16; ++z) {
    float a = fc_b[f];
    #pragma unroll
    for (int c = 0; c < 8; ++c) a += pooled[z][c] * fc_w[c * FF_DIM + f];
    hv[z] = softplus_f(a);
    mean += hv[z];
  }
  mean *= (1.0f / 16.0f);
  float var = 0.f;
  #pragma unroll
  for (int z = 0; z < 16; ++z) { float d = hv[z] - mean; var += d * d; }
  var *= (1.0f / 16.0f);
  float istd = 1.0f / sqrtf(var + 1e-5f);
  float g = bn_g[f], bb = bn_b[f], ow = out_w[f];
  float contrib[16];
  #pragma unroll
  for (int z = 0; z < 16; ++z)
    contrib[z] = softplus_f((hv[z] - mean) * istd * g + bb) * ow;

  const int lane = tid & 63, wv = tid >> 6;
  #pragma unroll
  for (int m = 32; m > 0; m >>= 1) {
    #pragma unroll
    for (int z = 0; z < 16; ++z) contrib[z] += __shfl_xor(contrib[z], m, 64);
  }
  if (lane == 0) {
    #pragma unroll
    for (int z = 0; z < 16; ++z) part[wv][z] = contrib[z];
  }
  __syncthreads();
  if (tid < 16) {
    float s = out_b[0];
    #pragma unroll
    for (int w8 = 0; w8 < 8; ++w8) s += part[w8][tid];
    out[tid] = 1.0f / (1.0f + expf(-s));
  }
}

extern "C" void kernel_launch(void* const* d_in, const int* in_sizes, int n_in,
                              void* d_out, int out_size, void* d_ws, size_t ws_size,
                              hipStream_t stream) {
  const float* xyz = (const float*)d_in[0];
  const int*   Z   = (const int*)d_in[1];
  const float* emb = (const float*)d_in[2];
  const float* c0[8]; const float* c1[8];
  for (int i = 0; i < 8; ++i) {
    c0[i] = (const float*)d_in[3 + i];
    c1[i] = (const float*)d_in[11 + i];
  }
  const float* fc_w  = (const float*)d_in[19];
  const float* fc_b  = (const float*)d_in[20];
  const float* bn_g  = (const float*)d_in[21];
  const float* bn_b  = (const float*)d_in[22];
  const float* out_w = (const float*)d_in[23];
  const float* out_b = (const float*)d_in[24];
  float* out = (float*)d_out;

  // ws layout (fp32 region first, then fp16 tables)
  float* wsf = (float*)d_ws;
  float* Wp = wsf;                                             // 4*151*152 f32
  float* f1 = Wp + (size_t)4 * WROWS * WPAD;                   // 16*286*4 f32
  float* f2 = f1 + (size_t)B_SZ * N_ATOM * 4;
  float* pool_sq = f2 + (size_t)B_SZ * N_ATOM * 4;             // 128 f32
  __half* tabh0 = (__half*)(pool_sq + 128);                    // NT*16 f16
  __half* tabh1 = tabh0 + (size_t)NT * 16;

  {
    dim3 g((WROWS * WPAD + 255) / 256, 4);
    prep_kernel<<<g, 256, 0, stream>>>(c0[2], c0[3], c0[4], c0[5],
                                       c1[2], c1[3], c1[4], c1[5], Wp);
  }

  table_kernel<<<2 * (NT / 8), 256, 0, stream>>>(
      c0[0], c0[1], c0[6], c0[7],
      c1[0], c1[1], c1[6], c1[7],
      Wp, tabh0, tabh1);

  const int conv_blocks = B_SZ * BLK_PER_Z;   // 1152
  conv_kernel<<<conv_blocks, 256, 0, stream>>>(xyz, Z, emb, (const float*)nullptr,
                                               tabh0, f1, 1);
  conv_kernel<<<conv_blocks, 256, 0, stream>>>(xyz, Z, emb, f1,
                                               tabh1, f2, 0);

  pool_kernel<<<B_SZ, 256, 0, stream>>>(f1, f2, pool_sq);

  tail_kernel<<<1, 512, 0, stream>>>(pool_sq, fc_w, fc_b, bn_g, bn_b,
                                     out_w, out_b, out);
}